// Round 3
// baseline (215.924 us; speedup 1.0000x reference)
//
#include <hip/hip_runtime.h>
#include <math.h>

// Problem constants (fixed by the reference setup_inputs): B=2, P=8192, K=16
#define PP    8192
#define NB    2
#define NPTS  16384          // NB * PP
#define KNN   16
#define EPSV  1e-17f

#define NCELL 4096           // 16^3 Morton cells per batch
#define NTILE 128            // tiles of 64 sorted points per batch
#define KEY_BIG 3.0e38f      // > any real key, finite

// ---- workspace layout (floats) ----------------------------------------------
// [idx 262144][dist 262144][phi 262144][region @786432: sort scratch, later nw]
// [n1 @1048576][n2 @1097728][part @1146880]
// Sort scratch (inside 786432..1048575, dead after knn; nw written by d2 after):
//   spts4  @786432  (16384 float4 = 65536 floats)
//   sid    @851968  (16384 ints)
//   aabb   @868352  (256 tiles * 2 float4 = 2048 floats)
//   hist   @870400  (8192 ints)
//   curs   @878592  (8192 ints)

__device__ __forceinline__ int cell_of(float x, float y, float z) {
    int cx = (int)floorf((x + 4.0f) * 2.0f); cx = min(15, max(0, cx));
    int cy = (int)floorf((y + 4.0f) * 2.0f); cy = min(15, max(0, cy));
    int cz = (int)floorf((z + 4.0f) * 2.0f); cz = min(15, max(0, cz));
    // 4-bit Morton spread: bit k -> bit 3k
    #define MORT4(v) (((v)&1) | (((v)&2)<<2) | (((v)&4)<<4) | (((v)&8)<<6))
    return MORT4(cx) | (MORT4(cy) << 1) | (MORT4(cz) << 2);
    #undef MORT4
}

// ---- K0a: zero histogram ----------------------------------------------------
__global__ void zero_kernel(int* __restrict__ hist) {
    int t = blockIdx.x * 256 + threadIdx.x;
    if (t < 2 * NCELL) hist[t] = 0;
}

// ---- K0b: cell histogram ----------------------------------------------------
__global__ void hist_kernel(const float* __restrict__ pts, int* __restrict__ hist) {
    int p = blockIdx.x * 256 + threadIdx.x;          // 0..16383
    if (p >= NPTS) return;
    int b = p >> 13;
    const float* q = pts + (size_t)p * 3;
    int code = cell_of(q[0], q[1], q[2]);
    atomicAdd(&hist[b * NCELL + code], 1);
}

// ---- K0c: global exclusive scan over 8192 cells (one block) -----------------
__global__ __launch_bounds__(1024) void scan_kernel(const int* __restrict__ hist,
                                                    int* __restrict__ curs) {
    __shared__ int lds[1024];
    const int t = threadIdx.x;
    int loc[8]; int s = 0;
#pragma unroll
    for (int k = 0; k < 8; ++k) { loc[k] = s; s += hist[t * 8 + k]; }
    lds[t] = s; __syncthreads();
    for (int off = 1; off < 1024; off <<= 1) {
        int v = (t >= off) ? lds[t - off] : 0;
        __syncthreads();
        lds[t] += v;
        __syncthreads();
    }
    const int excl = lds[t] - s;                     // exclusive prefix of thread t
#pragma unroll
    for (int k = 0; k < 8; ++k) curs[t * 8 + k] = excl + loc[k];
}

// ---- K0d: scatter into sorted order -----------------------------------------
__global__ void scatter_kernel(const float* __restrict__ pts, int* __restrict__ curs,
                               float4* __restrict__ spts4, int* __restrict__ sid) {
    int p = blockIdx.x * 256 + threadIdx.x;
    if (p >= NPTS) return;
    int b = p >> 13; int lp = p & (PP - 1);
    const float* q = pts + (size_t)p * 3;
    float x = q[0], y = q[1], z = q[2];
    int code = cell_of(x, y, z);
    int pos = atomicAdd(&curs[b * NCELL + code], 1); // global sorted position
    spts4[pos] = make_float4(x, y, z, x * x + y * y + z * z);
    sid[pos] = lp;
}

// ---- K0e: per-tile AABB (tiles of 64 sorted points) -------------------------
__global__ void aabb_kernel(const float4* __restrict__ spts4, float4* __restrict__ aabb) {
    const int gt = blockIdx.x;                       // 0..255 global tile
    const int lane = threadIdx.x;                    // 64 threads
    float4 c = spts4[gt * 64 + lane];
    float lx = c.x, ly = c.y, lz = c.z, hx = c.x, hy = c.y, hz = c.z;
#pragma unroll
    for (int m = 1; m < 64; m <<= 1) {
        lx = fminf(lx, __shfl_xor(lx, m, 64));
        ly = fminf(ly, __shfl_xor(ly, m, 64));
        lz = fminf(lz, __shfl_xor(lz, m, 64));
        hx = fmaxf(hx, __shfl_xor(hx, m, 64));
        hy = fmaxf(hy, __shfl_xor(hy, m, 64));
        hz = fmaxf(hz, __shfl_xor(hz, m, 64));
    }
    if (lane == 0) {
        aabb[2 * gt + 0] = make_float4(lx, ly, lz, 0.f);
        aabb[2 * gt + 1] = make_float4(hx, hy, hz, 0.f);
    }
}

// ---- K1: grid-pruned exact 16-NN + fused denoise1 ---------------------------
// Block: 8 waves, 64 queries (sorted positions q0..q0+63, same for all waves).
// Wave w handles candidates j = t*64 + (w + 8k) of each non-skipped tile t.
// Tile skipped by a wave iff trunc(boxdist^2) >= keys[15] for all 64 lanes
// (conservative in key space -> exact). Scan rotated to start at own tile.
#define TPB 512
__global__ __launch_bounds__(TPB) void knn_kernel(const float* __restrict__ pts,
                                                  const float* __restrict__ normals,
                                                  const float4* __restrict__ spts4,
                                                  const int* __restrict__ sid,
                                                  const float4* __restrict__ aabb,
                                                  int* __restrict__ out_idx,
                                                  float* __restrict__ out_dist,
                                                  float* __restrict__ phi_out,
                                                  float* __restrict__ n1_out) {
    __shared__ float4 lds_aabb[2 * NTILE];
    __shared__ float smerge[8 * KNN * 64];

    const int lane  = threadIdx.x & 63;
    const int wave  = threadIdx.x >> 6;
    const int batch = blockIdx.x >> 7;               // 0..1
    const int t_q   = blockIdx.x & (NTILE - 1);      // own tile 0..127
    const int sbase = batch * PP;                    // sorted-array batch offset

    if (threadIdx.x < 2 * NTILE)
        lds_aabb[threadIdx.x] = aabb[batch * 2 * NTILE + threadIdx.x];
    __syncthreads();

    // per-lane query (sorted position t_q*64 + lane)
    const float4 q4 = spts4[sbase + t_q * 64 + lane];
    const int    qid = sid[sbase + t_q * 64 + lane]; // original id 0..8191
    const float qx = q4.x, qy = q4.y, qz = q4.z, d2q = q4.w;

    float keys[KNN];
#pragma unroll
    for (int s = 0; s < KNN; ++s) keys[s] = KEY_BIG;

    for (int m = 0; m < NTILE; ++m) {
        int t = t_q + m; if (t >= NTILE) t -= NTILE;
        const float4 lo = lds_aabb[2 * t + 0];
        const float4 hi = lds_aabb[2 * t + 1];
        // per-lane lower bound dist^2 from query to tile AABB
        const float ax = fmaxf(fmaxf(lo.x - qx, qx - hi.x), 0.0f);
        const float ay = fmaxf(fmaxf(lo.y - qy, qy - hi.y), 0.0f);
        const float az = fmaxf(fmaxf(lo.z - qz, qz - hi.z), 0.0f);
        const float bd = ax * ax + ay * ay + az * az;
        const float bdk = __uint_as_float(__float_as_uint(bd) & 0xFFFFE000u);
        if (__ballot(bdk < keys[KNN - 1]) == 0ull) continue;

        const float4* cb = spts4 + (sbase + t * 64);
        const int*    sb = sid + (sbase + t * 64);
#pragma unroll
        for (int k = 0; k < 8; ++k) {
            const int jj = wave + 8 * k;             // wave-uniform
            const float4 c4 = cb[jj];
            const int sj = sb[jj];
            const float dot = __builtin_fmaf(qz, c4.z,
                              __builtin_fmaf(qy, c4.y, qx * c4.x));
            const float d = __builtin_fmaf(-2.0f, dot, d2q + c4.w);
            const float dc = fmaxf(d, 0.0f);
            unsigned int kb = (__float_as_uint(dc) & 0xFFFFE000u) | (unsigned int)sj;
            float key = __uint_as_float(kb);
            if (sj == qid) key = KEY_BIG;            // exclude self
#pragma unroll
            for (int s = KNN - 1; s >= 1; --s)
                keys[s] = __builtin_amdgcn_fmed3f(keys[s - 1], key, keys[s]);
            keys[0] = fminf(keys[0], key);
        }
    }

    __syncthreads();
#pragma unroll
    for (int s = 0; s < KNN; ++s) smerge[(wave * KNN + s) * 64 + lane] = keys[s];
    __syncthreads();

    if (wave == 0) {
        for (int w = 1; w < 8; ++w) {
#pragma unroll
            for (int s2 = 0; s2 < KNN; ++s2) {
                const float key = smerge[(w * KNN + s2) * 64 + lane];
#pragma unroll
                for (int s = KNN - 1; s >= 1; --s)
                    keys[s] = __builtin_amdgcn_fmed3f(keys[s - 1], key, keys[s]);
                keys[0] = fminf(keys[0], key);
            }
        }
        // epilogue: exact dists, idx, phi, n1 (fused denoise1). orig-id rows.
        const float* bp = pts + (size_t)batch * PP * 3;
        const float* bn = normals + (size_t)batch * PP * 3;
        const int qrow = batch * PP + qid;
        float d[KNN]; int jidx[KNN];
#pragma unroll
        for (int s = 0; s < KNN; ++s) {
            const int j = (int)(__float_as_uint(keys[s]) & 0x1FFFu);
            jidx[s] = j;
            out_idx[qrow * KNN + s] = j;
            const float x = bp[j * 3 + 0];
            const float y = bp[j * 3 + 1];
            const float z = bp[j * 3 + 2];
            const float dot = qx * x + qy * y + qz * z;
            const float dd = (d2q + (x * x + y * y + z * z)) - (dot + dot);
            const float dcl = fmaxf(dd, 0.0f);
            out_dist[qrow * KNN + s] = dcl;
            d[s] = dcl;
        }
        float d1 = d[0];
#pragma unroll
        for (int s = 1; s < KNN; ++s) d1 = fminf(d1, d[s]);
        float s0 = d1 * 8.0f;                        // 2 * FILTER_SCALE^2
        const float sden = (s0 < EPSV) ? EPSV : s0;
        float sphi = 0.f, nx = 0.f, ny = 0.f, nz = 0.f;
#pragma unroll
        for (int s = 0; s < KNN; ++s) {
            float w = fmaxf(1.0f - d[s] / sden, 0.0f);
            float w2 = w * w;
            float ph = w2 * w2;
            phi_out[qrow * KNN + s] = ph;
            const int j = jidx[s];
            nx += ph * bn[j * 3 + 0];
            ny += ph * bn[j * 3 + 1];
            nz += ph * bn[j * 3 + 2];
            sphi += ph;
        }
        const float den = (sphi < EPSV) ? EPSV : sphi;
        n1_out[qrow * 3 + 0] = nx / den;
        n1_out[qrow * 3 + 1] = ny / den;
        n1_out[qrow * 3 + 2] = nz / den;
    }
}

// ---- K3: normal_w + second denoise (n2) -------------------------------------
__global__ void denoise2_kernel(const int* __restrict__ idx,
                                const float* __restrict__ phi,
                                const float* __restrict__ n1,
                                float* __restrict__ nw_out,
                                float* __restrict__ n2_out) {
    const int q = blockIdx.x * blockDim.x + threadIdx.x;
    if (q >= NPTS) return;
    const int b = q >> 13;
    const int gbase = b * PP;
    const float INV_SIG = 1.0f / (0.75f * 0.75f);

    const float ax = n1[q * 3 + 0];
    const float ay = n1[q * 3 + 1];
    const float az = n1[q * 3 + 2];
    const float an = fmaxf(sqrtf(ax * ax + ay * ay + az * az), 1e-12f);
    const float rx = ax / an, ry = ay / an, rz = az / an;

    float swn = 0.f, ox = 0.f, oy = 0.f, oz = 0.f;
#pragma unroll
    for (int s = 0; s < KNN; ++s) {
        const int j = idx[q * KNN + s];
        const float bx = n1[(gbase + j) * 3 + 0];
        const float by = n1[(gbase + j) * 3 + 1];
        const float bz = n1[(gbase + j) * 3 + 2];
        const float bnn = fmaxf(sqrtf(bx * bx + by * by + bz * bz), 1e-12f);
        const float ux = bx / bnn - rx;
        const float uy = by / bnn - ry;
        const float uz = bz / bnn - rz;
        const float dd = ux * ux + uy * uy + uz * uz;
        const float nw = expf(-dd * INV_SIG);
        nw_out[q * KNN + s] = nw;
        const float wk = phi[q * KNN + s] * nw;
        ox += wk * bx;
        oy += wk * by;
        oz += wk * bz;
        swn += wk;
    }
    const float den = (swn < EPSV) ? EPSV : swn;
    n2_out[q * 3 + 0] = ox / den;
    n2_out[q * 3 + 1] = oy / den;
    n2_out[q * 3 + 2] = oz / den;
}

// ---- K4: weights_proj + point-to-plane loss, per-block partial sums ---------
__global__ void loss_kernel(const float* __restrict__ pts,
                            const int* __restrict__ idx,
                            const float* __restrict__ dist,
                            const float* __restrict__ phi,
                            const float* __restrict__ nw,
                            const float* __restrict__ n2,
                            float* __restrict__ partial) {
    const int q = blockIdx.x * 64 + threadIdx.x;
    const int b = q >> 13;
    const int il = q & (PP - 1);
    const float* bp = pts + (size_t)b * PP * 3;
    const int gbase = b * PP;

    const float px = bp[il * 3 + 0];
    const float py = bp[il * 3 + 1];
    const float pz = bp[il * 3 + 2];

    float d[KNN];
#pragma unroll
    for (int s = 0; s < KNN; ++s) d[s] = dist[q * KNN + s];
    float d1 = d[0];
#pragma unroll
    for (int s = 1; s < KNN; ++s) d1 = fminf(d1, d[s]);
    const float thresh = 4.0f * d1;

    float num = 0.f, den = 0.f;
#pragma unroll
    for (int s = 0; s < KNN; ++s) {
        float w = phi[q * KNN + s] * nw[q * KNN + s];
        if (d[s] > thresh) w = 0.f;
        const int j = idx[q * KNN + s];
        const float nx = n2[(gbase + j) * 3 + 0];
        const float ny = n2[(gbase + j) * 3 + 1];
        const float nz = n2[(gbase + j) * 3 + 2];
        const float dts = (bp[j * 3 + 0] - px) * nx +
                          (bp[j * 3 + 1] - py) * ny +
                          (bp[j * 3 + 2] - pz) * nz;
        num += dts * dts * w;
        den += w;
    }
    const float dd = (den < EPSV) ? EPSV : den;
    float loss = num / dd;

#pragma unroll
    for (int off = 32; off >= 1; off >>= 1) loss += __shfl_down(loss, off, 64);
    if (threadIdx.x == 0) partial[blockIdx.x] = loss;
}

// ---- K5: final mean ---------------------------------------------------------
__global__ void finalize_kernel(const float* __restrict__ partial,
                                float* __restrict__ out) {
    float v = partial[threadIdx.x] + partial[threadIdx.x + 64] +
              partial[threadIdx.x + 128] + partial[threadIdx.x + 192];
#pragma unroll
    for (int off = 32; off >= 1; off >>= 1) v += __shfl_down(v, off, 64);
    if (threadIdx.x == 0) out[0] = v / (float)NPTS;
}

// ---- launch -----------------------------------------------------------------
extern "C" void kernel_launch(void* const* d_in, const int* in_sizes, int n_in,
                              void* d_out, int out_size, void* d_ws, size_t ws_size,
                              hipStream_t stream) {
    const float* points  = (const float*)d_in[0];
    const float* normals = (const float*)d_in[1];
    float* out = (float*)d_out;

    float* wsf     = (float*)d_ws;
    int*   w_idx   = (int*)wsf;                      // @0       262144 ints
    float* w_dist  = wsf + 262144;                   // 262144 floats
    float* w_phi   = wsf + 524288;
    float* w_nw    = wsf + 786432;                   // also sort-scratch region
    float4* w_spts = (float4*)(wsf + 786432);        // 16384 float4
    int*   w_sid   = (int*)(wsf + 851968);           // 16384 ints
    float4* w_aabb = (float4*)(wsf + 868352);        // 512 float4
    int*   w_hist  = (int*)(wsf + 870400);           // 8192 ints
    int*   w_curs  = (int*)(wsf + 878592);           // 8192 ints
    float* w_n1    = wsf + 1048576;
    float* w_n2    = wsf + 1097728;
    float* w_part  = wsf + 1146880;

    zero_kernel<<<32, 256, 0, stream>>>(w_hist);
    hist_kernel<<<64, 256, 0, stream>>>(points, w_hist);
    scan_kernel<<<1, 1024, 0, stream>>>(w_hist, w_curs);
    scatter_kernel<<<64, 256, 0, stream>>>(points, w_curs, w_spts, w_sid);
    aabb_kernel<<<256, 64, 0, stream>>>(w_spts, w_aabb);
    knn_kernel<<<256, TPB, 0, stream>>>(points, normals, w_spts, w_sid, w_aabb,
                                        w_idx, w_dist, w_phi, w_n1);
    denoise2_kernel<<<NPTS / 256, 256, 0, stream>>>(w_idx, w_phi, w_n1, w_nw, w_n2);
    loss_kernel<<<NPTS / 64, 64, 0, stream>>>(points, w_idx, w_dist, w_phi, w_nw, w_n2, w_part);
    finalize_kernel<<<1, 64, 0, stream>>>(w_part, out);
}